// Round 4
// baseline (217.329 us; speedup 1.0000x reference)
//
#include <hip/hip_runtime.h>

// Centroid update: per-class mean of embed rows, blended with old centroid.
//   sums[c,:] = sum_{i: y[i]==c} embed[i,:]
//   out[c,:]  = 0.3 * sums[c,:]/count[c] + 0.7 * centroid[c,:]
//
// v4: G=4 classes per block (250 blocks x 256 threads), single y-scan per
// block binning into 4 LDS row-lists, then 4 sequential streaming gathers.
//
// Evidence so far: the timed window carries ~156 µs of harness re-poison
// fills (2 x 512 MiB @ 86% HBM peak, present even when d_ws is unused) —
// that floor is out of our control. Controllable portion by structure:
//   v0 rescan-per-class, 96 barriers: ~50 µs
//   v1/v2 counting-sort pipelines:    ~65-69 µs (launch gaps + 1-CU prep)
//   v3 rescan-per-class, 1 barrier:   ~56 µs (barriers were NOT the cost)
// Remaining modeled excess over the ~30 µs floor (launch + 22 µs gather +
// ~26% Poisson tail): the per-class y-rescan = 1000 x 128 KB = 128 MB of
// L2 reads + 32.7M compares that overlap nothing. G=4 cuts that phase 4x
// (32 MB, 8.2M range-checks) while keeping gather traffic identical
// (128 MiB embed read exactly once, 4 KB contiguous per row) and keeping
// ~every CU busy in the gather (250 blocks ~ 1/CU; 4 waves x 8 x 1 KB =
// 32 KB in flight/CU >> 9 KB needed for BW-bound).

#define BATCH       32768
#define EMBED_DIM   1024
#define NUM_CLASSES 1000
#define FACTOR      0.3f
#define G           4      // classes per block; 250 * 4 == 1000 exactly
#define MAXR        256    // per-class row capacity (Poisson(32.8), max ~60)

__global__ __launch_bounds__(256) void centroid_kernel(
    const float* __restrict__ embed,
    const int*   __restrict__ y,
    const float* __restrict__ centroid,
    float*       __restrict__ out)
{
    const int c0  = blockIdx.x * G;  // first class of this block
    const int tid = threadIdx.x;
    const int d0  = tid * 4;         // this thread's 4 dims (256*4 = 1024)

    __shared__ int rows[G][MAXR];    // row indices per class
    __shared__ int nm[G];            // per-class match counts

    if (tid < G) nm[tid] = 0;
    __syncthreads();

    // ---- Scan phase: one pass over all 32768 labels, coalesced int4.
    // y is 128 KB -> L2-resident; device-wide this phase now reads only
    // 250 x 128 KB = 32 MB (~1 µs at L2 BW). One unsigned range-check
    // classifies a label against all 4 classes at once.
    #pragma unroll 8
    for (int base = 0; base < BATCH; base += 1024) {
        const int idx = base + d0;
        const int4 v = *reinterpret_cast<const int4*>(y + idx);
        unsigned u;
        u = (unsigned)(v.x - c0); if (u < G) { int p = atomicAdd(&nm[u], 1); rows[u][p] = idx + 0; }
        u = (unsigned)(v.y - c0); if (u < G) { int p = atomicAdd(&nm[u], 1); rows[u][p] = idx + 1; }
        u = (unsigned)(v.z - c0); if (u < G) { int p = atomicAdd(&nm[u], 1); rows[u][p] = idx + 2; }
        u = (unsigned)(v.w - c0); if (u < G) { int p = atomicAdd(&nm[u], 1); rows[u][p] = idx + 3; }
    }
    __syncthreads();                 // the one barrier

    // ---- Gather phase: per class, stream its rows with 8 independent
    // 1 KB/wave loads in flight (128 B/lane outstanding -> BW-bound).
    for (int g = 0; g < G; ++g) {
        const int m = nm[g];         // same value block-wide (~33 avg)
        const int* rl = rows[g];

        float4 acc = make_float4(0.f, 0.f, 0.f, 0.f);
        int j = 0;
        for (; j + 8 <= m; j += 8) {
            float4 v[8];
            #pragma unroll
            for (int u = 0; u < 8; ++u) {
                const int r = rl[j + u];   // LDS broadcast — no bank conflict
                v[u] = *reinterpret_cast<const float4*>(
                    embed + (size_t)r * EMBED_DIM + d0);
            }
            #pragma unroll
            for (int u = 0; u < 8; ++u) {
                acc.x += v[u].x; acc.y += v[u].y;
                acc.z += v[u].z; acc.w += v[u].w;
            }
        }
        for (; j < m; ++j) {
            const int r = rl[j];
            const float4 v = *reinterpret_cast<const float4*>(
                embed + (size_t)r * EMBED_DIM + d0);
            acc.x += v.x; acc.y += v.y; acc.z += v.z; acc.w += v.w;
        }

        // Epilogue: mean, blend, store. m==0 -> 0*inf = NaN, matching ref.
        const float inv = 1.0f / (float)m;
        const size_t o = (size_t)(c0 + g) * EMBED_DIM + d0;
        const float4 cen = *reinterpret_cast<const float4*>(centroid + o);
        float4 res;
        res.x = FACTOR * (acc.x * inv) + (1.0f - FACTOR) * cen.x;
        res.y = FACTOR * (acc.y * inv) + (1.0f - FACTOR) * cen.y;
        res.z = FACTOR * (acc.z * inv) + (1.0f - FACTOR) * cen.z;
        res.w = FACTOR * (acc.w * inv) + (1.0f - FACTOR) * cen.w;
        *reinterpret_cast<float4*>(out + o) = res;
    }
}

extern "C" void kernel_launch(void* const* d_in, const int* in_sizes, int n_in,
                              void* d_out, int out_size, void* d_ws, size_t ws_size,
                              hipStream_t stream) {
    const float* embed    = (const float*)d_in[0];  // [32768, 1024]
    const int*   y        = (const int*)d_in[1];    // [32768] int32
    const float* centroid = (const float*)d_in[2];  // [1000, 1024]
    float*       out      = (float*)d_out;          // [1000, 1024]

    centroid_kernel<<<NUM_CLASSES / G, 256, 0, stream>>>(embed, y, centroid, out);
}

// Round 5
// 212.639 us; speedup vs baseline: 1.0221x; 1.0221x over previous
//
#include <hip/hip_runtime.h>

// Centroid update: per-class mean of embed rows, blended with old centroid.
//   sums[c,:] = sum_{i: y[i]==c} embed[i,:]
//   out[c,:]  = 0.3 * sums[c,:]/count[c] + 0.7 * centroid[c,:]
//
// v5: memory-latency attack. Round-4 rocprof (first time our kernel was
// visible): 78 µs at 938 GB/s (11.7% peak), VALUBusy 2.5%, Occupancy 9.2%,
// VGPR=36. Diagnosis: latency-bound at ~15% duty — 250 blocks gave only
// 3.9 waves/CU, and the 36-VGPR allocation proves the compiler serialized
// the "8-deep" gather (8xfloat4 alone needs 32 regs). Burst-drain-burst.
// Fix:
//   1. 1000 blocks (1 class/block, 256 thr) -> 15.6 waves/CU.
//   2. __launch_bounds__(256, 4): VGPR cap 128, 4 blocks/CU co-resident.
//   3. Ping-pong register pipeline in the gather: two 8-row float4 groups,
//      consume-oldest/refill rotation -> 8-16 KB outstanding per wave
//      CONTINUOUSLY. ~16 waves/CU x ~12 KB >> 9 KB BW*latency product.
// Scan phase (each block re-reads y, 128 KB, L2-resident) is ~4-6 µs
// device-wide — kept: cheaper than any multi-kernel prep (v1/v2 lesson).

#define BATCH       32768
#define EMBED_DIM   1024
#define NUM_CLASSES 1000
#define FACTOR      0.3f
#define MAXR        128    // Poisson(32.8) max ~60; 128 is bulletproof

__global__ __launch_bounds__(256, 4) void centroid_kernel(
    const float* __restrict__ embed,
    const int*   __restrict__ y,
    const float* __restrict__ centroid,
    float*       __restrict__ out)
{
    const int c   = blockIdx.x;      // class this block reduces
    const int tid = threadIdx.x;
    const int d0  = tid * 4;         // this thread's 4 dims (256*4 = 1024)

    __shared__ int rows[MAXR];       // all matched row indices for class c
    __shared__ int nmatch;

    if (tid == 0) nmatch = 0;

    // Hoisted centroid load — overlaps the scan.
    const size_t o = (size_t)c * EMBED_DIM + d0;
    const float4 cen = *reinterpret_cast<const float4*>(centroid + o);

    __syncthreads();

    // ---- Scan: 32768 labels, coalesced int4, 8 loads in flight, no
    // per-chunk barriers. y is 128 KB -> L2-resident after first touch.
    #pragma unroll 8
    for (int base = 0; base < BATCH; base += 1024) {
        const int idx = base + d0;
        const int4 v = *reinterpret_cast<const int4*>(y + idx);
        if (v.x == c) { int p = atomicAdd(&nmatch, 1); rows[p] = idx + 0; }
        if (v.y == c) { int p = atomicAdd(&nmatch, 1); rows[p] = idx + 1; }
        if (v.z == c) { int p = atomicAdd(&nmatch, 1); rows[p] = idx + 2; }
        if (v.w == c) { int p = atomicAdd(&nmatch, 1); rows[p] = idx + 3; }
    }
    __syncthreads();                 // the one barrier

    const int m  = nmatch;           // block-uniform (~33 avg, max ~60)
    const int ng = m >> 3;           // full groups of 8 rows

    float4 acc = make_float4(0.f, 0.f, 0.f, 0.f);
    float4 va[8], vb[8];             // two in-flight groups: 64 VGPRs

    // All loop indices into va/vb are compile-time constants (full unroll)
    // so both groups stay in registers (no scratch).
#define LOADG(dst, gbase)                                                   \
    {                                                                       \
        _Pragma("unroll")                                                   \
        for (int u = 0; u < 8; ++u) {                                       \
            const int r = rows[(gbase) + u];   /* LDS broadcast */          \
            dst[u] = *reinterpret_cast<const float4*>(                      \
                embed + (size_t)r * EMBED_DIM + d0);                        \
        }                                                                   \
    }
#define CONSG(src)                                                          \
    {                                                                       \
        _Pragma("unroll")                                                   \
        for (int u = 0; u < 8; ++u) {                                       \
            acc.x += src[u].x; acc.y += src[u].y;                           \
            acc.z += src[u].z; acc.w += src[u].w;                           \
        }                                                                   \
    }

    if (ng > 0) {
        LOADG(va, 0);
        if (ng > 1) LOADG(vb, 8);
        int loaded = (ng > 1) ? 2 : 1;
        // Consume oldest group, immediately refill it: waiting on va's 8
        // loads leaves vb's 8 still outstanding -> continuous MLP.
        for (int consumed = 0; consumed < ng; ++consumed) {
            if ((consumed & 1) == 0) {
                CONSG(va);
                if (loaded < ng) { LOADG(va, loaded * 8); ++loaded; }
            } else {
                CONSG(vb);
                if (loaded < ng) { LOADG(vb, loaded * 8); ++loaded; }
            }
        }
    }
    // Tail (m & 7 rows).
    for (int j = ng * 8; j < m; ++j) {
        const int r = rows[j];
        const float4 v = *reinterpret_cast<const float4*>(
            embed + (size_t)r * EMBED_DIM + d0);
        acc.x += v.x; acc.y += v.y; acc.z += v.z; acc.w += v.w;
    }
#undef LOADG
#undef CONSG

    // ---- Epilogue: mean, blend, store. m==0 -> 0*inf = NaN, matching ref.
    const float inv = 1.0f / (float)m;
    float4 res;
    res.x = FACTOR * (acc.x * inv) + (1.0f - FACTOR) * cen.x;
    res.y = FACTOR * (acc.y * inv) + (1.0f - FACTOR) * cen.y;
    res.z = FACTOR * (acc.z * inv) + (1.0f - FACTOR) * cen.z;
    res.w = FACTOR * (acc.w * inv) + (1.0f - FACTOR) * cen.w;
    *reinterpret_cast<float4*>(out + o) = res;
}

extern "C" void kernel_launch(void* const* d_in, const int* in_sizes, int n_in,
                              void* d_out, int out_size, void* d_ws, size_t ws_size,
                              hipStream_t stream) {
    const float* embed    = (const float*)d_in[0];  // [32768, 1024]
    const int*   y        = (const int*)d_in[1];    // [32768] int32
    const float* centroid = (const float*)d_in[2];  // [1000, 1024]
    float*       out      = (float*)d_out;          // [1000, 1024]

    centroid_kernel<<<NUM_CLASSES, 256, 0, stream>>>(embed, y, centroid, out);
}